// Round 1
// baseline (101.908 us; speedup 1.0000x reference)
//
#include <hip/hip_runtime.h>

// CubicalEcc: x [8,3,224,224] f32 -> ecc [8,3,32] f32
// Per-pixel Euler increment: every cell (vertex/edge/face) is attributed to
// its unique owning pixel (argmin over incident pixels, ties by memory order).
// chi(t) = sum_p [v_p <= t] * delta_p,  delta_p = 1 + nV(p) - nE(p).
// Exact, including ties. One signed histogram update per pixel.
//
// SINGLE-LAUNCH fusion (launch-overhead-bound regime): each block writes its
// 32-bin partial hist to ws, then release-stores TWO block-dependent flag
// words. The blockIdx.x==0 block per image spins on all 56 flag pairs
// (agent-scope acquire, cross-XCD safe), reduces, prefix-sums, writes out.
// Poison-safe: a constant poison fill pattern cannot equal two distinct
// expected flag values in the same word stream. Deadlock-free: 24 spinner
// blocks << 256 CUs (all 1344 blocks are in fact co-resident).

#define HH 224
#define WW 224
#define STEPS 32
#define NBC 24     // 8*3 images
#define RBLK 56    // blocks per image; each covers 4 pixel rows

// ws layout (ints)
#define P_OFF 0                          // partial[NBC][RBLK][STEPS]
#define F1_OFF (NBC * RBLK * STEPS)      // flag1[NBC*RBLK]
#define F2_OFF (F1_OFF + NBC * RBLK)     // flag2[NBC*RBLK]

__device__ __forceinline__ int flag1_val(int id) {
    return (int)(0xA5C3170Fu ^ (unsigned)id);
}
__device__ __forceinline__ int flag2_val(int id) {
    return (int)(0x3C96E1B5u + (unsigned)id * 2654435761u);
}

// smallest k in [0,32) with v <= t_k, t_k = -2 + k*(4/31); 32 => never counted
__device__ __forceinline__ int bin_of(float v) {
    int k = (int)ceilf(fmaf(v, 7.75f, 15.5f));  // (v+2)*31/4
    return max(0, min(32, k));
}

__global__ __launch_bounds__(256) void ecc_fused(const float* __restrict__ x,
                                                 int* __restrict__ ws,
                                                 float* __restrict__ out) {
    __shared__ int whist[4 * STEPS];  // one 32-bin hist per wave
    __shared__ int red[8][STEPS];
    const int tid = threadIdx.x;
    if (tid < 4 * STEPS) whist[tid] = 0;
    __syncthreads();

    const int lane = tid & 63;
    const int r = tid >> 6;
    const int bx = blockIdx.x;
    const int bc = blockIdx.y;
    const int i = bx * 4 + r;  // pixel row, always < 224
    const float* img = x + (size_t)bc * (HH * WW);
    int* wh = whist + r * STEPS;
    const float INF = __builtin_huge_valf();

    if (lane < 56) {
        const int j0 = lane * 4;  // this thread: pixels (i, j0..j0+3)
        const float* rowC = img + i * WW;
        const float4 c4 = *(const float4*)(rowC + j0);
        const float cL = (j0 > 0) ? rowC[j0 - 1] : INF;
        const float cR = (j0 + 4 < WW) ? rowC[j0 + 4] : INF;
        float4 m4 = make_float4(INF, INF, INF, INF);
        float mL = INF, mR = INF;
        if (i > 0) {
            const float* rowM = rowC - WW;
            m4 = *(const float4*)(rowM + j0);
            mL = (j0 > 0) ? rowM[j0 - 1] : INF;
            mR = (j0 + 4 < WW) ? rowM[j0 + 4] : INF;
        }
        float4 p4 = make_float4(INF, INF, INF, INF);
        float pL = INF, pR = INF;
        if (i + 1 < HH) {
            const float* rowP = rowC + WW;
            p4 = *(const float4*)(rowP + j0);
            pL = (j0 > 0) ? rowP[j0 - 1] : INF;
            pR = (j0 + 4 < WW) ? rowP[j0 + 4] : INF;
        }

        const float cm[6] = {cL, c4.x, c4.y, c4.z, c4.w, cR};
        const float mm[6] = {mL, m4.x, m4.y, m4.z, m4.w, mR};
        const float pm[6] = {pL, p4.x, p4.y, p4.z, p4.w, pR};

        #pragma unroll
        for (int c = 0; c < 4; ++c) {
            const float v = cm[c + 1];
            // earlier neighbors (strict <): UL, U, UR, L
            const bool bUL = v < mm[c];
            const bool bU  = v < mm[c + 1];
            const bool bUR = v < mm[c + 2];
            const bool bL  = v < cm[c];
            // later neighbors (<=): R, DL, D, DR
            const bool bR  = v <= cm[c + 2];
            const bool bDL = v <= pm[c];
            const bool bD  = v <= pm[c + 1];
            const bool bDR = v <= pm[c + 2];
            const int nE = (int)bU + (int)bL + (int)bR + (int)bD;
            const int nV = (int)(bUL & bU & bL) + (int)(bU & bUR & bR) +
                           (int)(bL & bDL & bD) + (int)(bR & bD & bDR);
            const int d = 1 + nV - nE;
            const int k = bin_of(v);
            if (d != 0 && k < STEPS) atomicAdd(&wh[k], d);
        }
    }
    __syncthreads();

    // publish this block's 32-bin partial (agent scope: cross-XCD visible)
    const int id = bc * RBLK + bx;
    if (tid < STEPS) {
        const int s = whist[tid] + whist[STEPS + tid] +
                      whist[2 * STEPS + tid] + whist[3 * STEPS + tid];
        __hip_atomic_store(&ws[P_OFF + id * STEPS + tid], s,
                           __ATOMIC_RELAXED, __HIP_MEMORY_SCOPE_AGENT);
    }
    __syncthreads();
    if (tid == 0) {
        __threadfence();  // agent-scope fence: partials visible before flags
        __hip_atomic_store(&ws[F1_OFF + id], flag1_val(id),
                           __ATOMIC_RELEASE, __HIP_MEMORY_SCOPE_AGENT);
        __hip_atomic_store(&ws[F2_OFF + id], flag2_val(id),
                           __ATOMIC_RELEASE, __HIP_MEMORY_SCOPE_AGENT);
    }

    if (bx != 0) return;

    // ---- reducer: one block per image ----
    // wait for all 56 partials of this bc (value-coded double flags)
    if (tid < RBLK) {
        const int jid = bc * RBLK + tid;
        const int e1 = flag1_val(jid);
        const int e2 = flag2_val(jid);
        while (__hip_atomic_load(&ws[F1_OFF + jid], __ATOMIC_ACQUIRE,
                                 __HIP_MEMORY_SCOPE_AGENT) != e1) {}
        while (__hip_atomic_load(&ws[F2_OFF + jid], __ATOMIC_ACQUIRE,
                                 __HIP_MEMORY_SCOPE_AGENT) != e2) {}
    }
    __syncthreads();

    // sum 56 partials per bin: 8 groups x 7 blocks each
    const int bin = tid & 31;
    const int g = tid >> 5;  // 0..7
    int s = 0;
    #pragma unroll
    for (int q = 0; q < 7; ++q) {
        const int j = g * 7 + q;
        s += __hip_atomic_load(&ws[P_OFF + (bc * RBLK + j) * STEPS + bin],
                               __ATOMIC_RELAXED, __HIP_MEMORY_SCOPE_AGENT);
    }
    red[g][bin] = s;
    __syncthreads();

    if (tid < STEPS) {
        int tot = 0;
        #pragma unroll
        for (int q = 0; q < 8; ++q) tot += red[q][tid];
        whist[tid] = tot;  // reuse whist as the per-bin total
    }
    __syncthreads();

    if (tid < STEPS) {
        int acc = 0;
        for (int j = 0; j <= tid; ++j) acc += whist[j];
        out[bc * STEPS + tid] = (float)acc;
    }
}

extern "C" void kernel_launch(void* const* d_in, const int* in_sizes, int n_in,
                              void* d_out, int out_size, void* d_ws, size_t ws_size,
                              hipStream_t stream) {
    const float* x = (const float*)d_in[0];
    float* out = (float*)d_out;
    int* ws = (int*)d_ws;  // (43008 + 2*1344) ints = 182784 bytes used

    ecc_fused<<<dim3(RBLK, NBC), 256, 0, stream>>>(x, ws, out);
}

// Round 2
// 76.250 us; speedup vs baseline: 1.3365x; 1.3365x over previous
//
#include <hip/hip_runtime.h>

// CubicalEcc: x [8,3,224,224] f32 -> ecc [8,3,32] f32
// Per-pixel Euler increment: every cell (vertex/edge/face) is attributed to
// its unique owning pixel (argmin over incident pixels, ties by memory order).
// chi(t) = sum_p [v_p <= t] * delta_p,  delta_p = 1 + nV(p) - nE(p),
// where "p beats q": v_p < v_q if q earlier in row-major order, <= if later.
// Out-of-image neighbors are +inf. Exact, including ties.
//
// SINGLE LAUNCH, ZERO cross-block communication (round-1 post-mortem: flag
// spin sync cost 54us; a second launch costs ~5us; block-local is ~0).
// One block per image: 1024 threads = 16 waves; 14 sweeps of 16 rows each.
// Per-wave private LDS histogram -> in-block reduce -> prefix -> out.
// No workspace use at all (ws stays poisoned, we never read it).

#define HH 224
#define WW 224
#define STEPS 32
#define NBC 24          // 8*3 images
#define NW 16           // waves per block
#define ITERS (HH / NW) // 14 row-sweeps

// smallest k in [0,32) with v <= t_k, t_k = -2 + k*(4/31); 32 => never counted
__device__ __forceinline__ int bin_of(float v) {
    int k = (int)ceilf(fmaf(v, 7.75f, 15.5f));  // (v+2)*31/4
    return max(0, min(32, k));
}

__global__ __launch_bounds__(1024) void ecc_onepass(const float* __restrict__ x,
                                                    float* __restrict__ out) {
    __shared__ int whist[NW * STEPS];  // one 32-bin hist per wave
    __shared__ int red[STEPS];
    const int tid = threadIdx.x;
    if (tid < NW * STEPS) whist[tid] = 0;
    __syncthreads();

    const int lane = tid & 63;
    const int w = tid >> 6;           // wave 0..15
    const int bc = blockIdx.x;        // image 0..23
    const float* img = x + (size_t)bc * (HH * WW);
    int* wh = whist + w * STEPS;
    const float INF = __builtin_huge_valf();

    if (lane < 56) {
        const int j0 = lane * 4;      // this thread: pixels (i, j0..j0+3)
        #pragma unroll 2
        for (int it = 0; it < ITERS; ++it) {
            const int i = it * NW + w;  // row, 0..223, each exactly once
            const float* rowC = img + i * WW;
            const float4 c4 = *(const float4*)(rowC + j0);
            const float cL = (j0 > 0) ? rowC[j0 - 1] : INF;
            const float cR = (j0 + 4 < WW) ? rowC[j0 + 4] : INF;
            float4 m4 = make_float4(INF, INF, INF, INF);
            float mL = INF, mR = INF;
            if (i > 0) {
                const float* rowM = rowC - WW;
                m4 = *(const float4*)(rowM + j0);
                mL = (j0 > 0) ? rowM[j0 - 1] : INF;
                mR = (j0 + 4 < WW) ? rowM[j0 + 4] : INF;
            }
            float4 p4 = make_float4(INF, INF, INF, INF);
            float pL = INF, pR = INF;
            if (i + 1 < HH) {
                const float* rowP = rowC + WW;
                p4 = *(const float4*)(rowP + j0);
                pL = (j0 > 0) ? rowP[j0 - 1] : INF;
                pR = (j0 + 4 < WW) ? rowP[j0 + 4] : INF;
            }

            const float cm[6] = {cL, c4.x, c4.y, c4.z, c4.w, cR};
            const float mm[6] = {mL, m4.x, m4.y, m4.z, m4.w, mR};
            const float pm[6] = {pL, p4.x, p4.y, p4.z, p4.w, pR};

            #pragma unroll
            for (int c = 0; c < 4; ++c) {
                const float v = cm[c + 1];
                // earlier neighbors (strict <): UL, U, UR, L
                const bool bUL = v < mm[c];
                const bool bU  = v < mm[c + 1];
                const bool bUR = v < mm[c + 2];
                const bool bL  = v < cm[c];
                // later neighbors (<=): R, DL, D, DR
                const bool bR  = v <= cm[c + 2];
                const bool bDL = v <= pm[c];
                const bool bD  = v <= pm[c + 1];
                const bool bDR = v <= pm[c + 2];
                const int nE = (int)bU + (int)bL + (int)bR + (int)bD;
                const int nV = (int)(bUL & bU & bL) + (int)(bU & bUR & bR) +
                               (int)(bL & bDL & bD) + (int)(bR & bD & bDR);
                const int d = 1 + nV - nE;
                const int k = bin_of(v);
                if (d != 0 && k < STEPS) atomicAdd(&wh[k], d);
            }
        }
    }
    __syncthreads();

    // reduce 16 per-wave histograms -> per-bin totals
    if (tid < STEPS) {
        int tot = 0;
        #pragma unroll
        for (int q = 0; q < NW; ++q) tot += whist[q * STEPS + tid];
        red[tid] = tot;
    }
    __syncthreads();

    // inclusive prefix over bins -> Euler characteristic curve
    if (tid < STEPS) {
        int acc = 0;
        for (int j = 0; j <= tid; ++j) acc += red[j];
        out[bc * STEPS + tid] = (float)acc;
    }
}

extern "C" void kernel_launch(void* const* d_in, const int* in_sizes, int n_in,
                              void* d_out, int out_size, void* d_ws, size_t ws_size,
                              hipStream_t stream) {
    const float* x = (const float*)d_in[0];
    float* out = (float*)d_out;
    (void)d_ws; (void)ws_size;  // workspace intentionally unused

    ecc_onepass<<<NBC, 1024, 0, stream>>>(x, out);
}